// Round 1
// baseline (16907.864 us; speedup 1.0000x reference)
//
#include <hip/hip_runtime.h>

#define TT 20
#define HH 64

__device__ __forceinline__ float fast_tanh(float a) {
    // tanh(a) = (e-1)/(e+1), e = exp(2a) = 2^(a*2/ln2). Clamp avoids inf/inf.
    a = fminf(fmaxf(a, -12.0f), 12.0f);
    float e = __builtin_amdgcn_exp2f(a * 2.885390081777927f);
    return (e - 1.0f) * __builtin_amdgcn_rcpf(e + 1.0f);
}

__global__ void k_dinit(float* __restrict__ deg, int N) {
    int n = blockIdx.x * blockDim.x + threadIdx.x;
    if (n < N) deg[n] = 1.0f;  // self-loop
}

__global__ void k_deg(const int* __restrict__ ei, float* __restrict__ deg, int E) {
    int e = blockIdx.x * blockDim.x + threadIdx.x;
    if (e < E) atomicAdd(&deg[ei[2 * e + 1]], 1.0f);
}

__global__ __launch_bounds__(128, 2) void k_rnn(
    const float* __restrict__ x,
    const float* __restrict__ W_ih, const float* __restrict__ b_ih,
    const float* __restrict__ W_hh, const float* __restrict__ b_hh,
    const float* __restrict__ W_gcn, const float* __restrict__ b_gcn,
    const float* __restrict__ deg,
    float* __restrict__ xw, float* __restrict__ agg, int N)
{
    __shared__ float sW[HH * HH];   // W_hh during RNN, W_gcn afterwards
    __shared__ float sWih[HH];
    __shared__ float sBsum[HH];
    __shared__ float sBgcn[HH];
    const int tid = threadIdx.x;

    for (int i = tid; i < HH * HH / 4; i += blockDim.x)
        ((float4*)sW)[i] = ((const float4*)W_hh)[i];
    if (tid < HH) {
        sWih[tid]  = W_ih[tid];
        sBsum[tid] = b_ih[tid] + b_hh[tid];
        sBgcn[tid] = b_gcn[tid];
    }
    __syncthreads();

    const int nn = blockIdx.x * blockDim.x + tid;
    const bool store = nn < N;
    const int n = store ? nn : (N - 1);  // clamp so inactive lanes stay in step for barriers
    const float* xrow = x + (size_t)n * TT;

    float h[HH];
#pragma unroll
    for (int j = 0; j < HH; ++j) h[j] = 0.0f;

    for (int t = 0; t < TT; ++t) {
        const float xt = xrow[t];   // scalar load per step (keeps body i-cache-sized, no dyn reg index)
        float hn[HH];
#pragma unroll
        for (int j = 0; j < HH; ++j) {
            float acc = fmaf(xt, sWih[j], sBsum[j]);
            const float4* wr = (const float4*)(sW + j * HH);
#pragma unroll
            for (int k = 0; k < HH / 4; ++k) {
                const float4 w = wr[k];
                acc = fmaf(h[4 * k + 0], w.x, acc);
                acc = fmaf(h[4 * k + 1], w.y, acc);
                acc = fmaf(h[4 * k + 2], w.z, acc);
                acc = fmaf(h[4 * k + 3], w.w, acc);
            }
            hn[j] = fast_tanh(acc);
        }
#pragma unroll
        for (int j = 0; j < HH; ++j) h[j] = hn[j];
    }

    // swap LDS to W_gcn
    __syncthreads();
    for (int i = tid; i < HH * HH / 4; i += blockDim.x)
        ((float4*)sW)[i] = ((const float4*)W_gcn)[i];
    __syncthreads();

    const float di = __frsqrt_rn(deg[n]);
    const float invd = di * di;   // self-loop norm = dinv^2
    float4* xwp  = (float4*)(xw  + (size_t)n * HH);
    float4* aggp = (float4*)(agg + (size_t)n * HH);

#pragma unroll
    for (int j = 0; j < HH; j += 4) {
        float a0 = 0.f, a1 = 0.f, a2 = 0.f, a3 = 0.f;
        const float4* w0 = (const float4*)(sW + (j + 0) * HH);
        const float4* w1 = (const float4*)(sW + (j + 1) * HH);
        const float4* w2 = (const float4*)(sW + (j + 2) * HH);
        const float4* w3 = (const float4*)(sW + (j + 3) * HH);
#pragma unroll
        for (int k = 0; k < HH / 4; ++k) {
            const float4 q0 = w0[k], q1 = w1[k], q2 = w2[k], q3 = w3[k];
            const float h0 = h[4 * k + 0], h1 = h[4 * k + 1], h2 = h[4 * k + 2], h3 = h[4 * k + 3];
            a0 = fmaf(h0, q0.x, a0); a0 = fmaf(h1, q0.y, a0); a0 = fmaf(h2, q0.z, a0); a0 = fmaf(h3, q0.w, a0);
            a1 = fmaf(h0, q1.x, a1); a1 = fmaf(h1, q1.y, a1); a1 = fmaf(h2, q1.z, a1); a1 = fmaf(h3, q1.w, a1);
            a2 = fmaf(h0, q2.x, a2); a2 = fmaf(h1, q2.y, a2); a2 = fmaf(h2, q2.z, a2); a2 = fmaf(h3, q2.w, a2);
            a3 = fmaf(h0, q3.x, a3); a3 = fmaf(h1, q3.y, a3); a3 = fmaf(h2, q3.z, a3); a3 = fmaf(h3, q3.w, a3);
        }
        if (store) {
            float4 o; o.x = a0; o.y = a1; o.z = a2; o.w = a3;
            xwp[j / 4] = o;
            float4 g;
            g.x = fmaf(a0, invd, sBgcn[j + 0]);
            g.y = fmaf(a1, invd, sBgcn[j + 1]);
            g.z = fmaf(a2, invd, sBgcn[j + 2]);
            g.w = fmaf(a3, invd, sBgcn[j + 3]);
            aggp[j / 4] = g;
        }
    }
}

__global__ void k_scatter(const int* __restrict__ ei, const float* __restrict__ deg,
                          const float* __restrict__ xw, float* __restrict__ agg, int E)
{
    int gid = blockIdx.x * blockDim.x + threadIdx.x;
    int e = gid >> 4;
    int l = gid & 15;
    if (e >= E) return;
    int s = ei[2 * e + 0];
    int d = ei[2 * e + 1];
    float norm = __frsqrt_rn(deg[s]) * __frsqrt_rn(deg[d]);
    const float4 v = *(const float4*)(xw + (size_t)s * HH + l * 4);
    float* ap = agg + (size_t)d * HH + l * 4;
    atomicAdd(ap + 0, v.x * norm);
    atomicAdd(ap + 1, v.y * norm);
    atomicAdd(ap + 2, v.z * norm);
    atomicAdd(ap + 3, v.w * norm);
}

__global__ void k_out(const float* __restrict__ agg, const float* __restrict__ Wfc,
                      const float* __restrict__ bfc, float* __restrict__ out, int N)
{
    __shared__ float sw[HH];
    if (threadIdx.x < HH) sw[threadIdx.x] = Wfc[threadIdx.x];
    __syncthreads();
    int n = blockIdx.x * blockDim.x + threadIdx.x;
    if (n >= N) return;
    const float4* ap = (const float4*)(agg + (size_t)n * HH);
    float acc = bfc[0];
#pragma unroll
    for (int k = 0; k < HH / 4; ++k) {
        float4 a = ap[k];
        acc = fmaf(a.x, sw[4 * k + 0], acc);
        acc = fmaf(a.y, sw[4 * k + 1], acc);
        acc = fmaf(a.z, sw[4 * k + 2], acc);
        acc = fmaf(a.w, sw[4 * k + 3], acc);
    }
    out[n] = acc;
}

extern "C" void kernel_launch(void* const* d_in, const int* in_sizes, int n_in,
                              void* d_out, int out_size, void* d_ws, size_t ws_size,
                              hipStream_t stream)
{
    const float* x     = (const float*)d_in[0];
    const int*   ei    = (const int*)d_in[1];
    const float* W_ih  = (const float*)d_in[2];
    const float* b_ih  = (const float*)d_in[3];
    const float* W_hh  = (const float*)d_in[4];
    const float* b_hh  = (const float*)d_in[5];
    const float* W_gcn = (const float*)d_in[6];
    const float* b_gcn = (const float*)d_in[7];
    const float* W_fc  = (const float*)d_in[8];
    const float* b_fc  = (const float*)d_in[9];
    float* out = (float*)d_out;

    const int N = in_sizes[0] / TT;
    const int E = in_sizes[1] / 2;

    char* ws = (char*)d_ws;
    float* deg = (float*)ws;                                      // N floats
    size_t xw_off  = (size_t)1 << 20;                             // 1 MB
    size_t xw_sz   = (size_t)N * HH * sizeof(float);
    size_t agg_off = xw_off + ((xw_sz + 1023) / 1024) * 1024;
    float* xw  = (float*)(ws + xw_off);
    float* agg = (float*)(ws + agg_off);

    k_dinit<<<(N + 255) / 256, 256, 0, stream>>>(deg, N);
    k_deg<<<(E + 255) / 256, 256, 0, stream>>>(ei, deg, E);
    k_rnn<<<(N + 127) / 128, 128, 0, stream>>>(x, W_ih, b_ih, W_hh, b_hh,
                                               W_gcn, b_gcn, deg, xw, agg, N);
    long long tot = (long long)E * 16;
    k_scatter<<<(int)((tot + 255) / 256), 256, 0, stream>>>(ei, deg, xw, agg, E);
    k_out<<<(N + 255) / 256, 256, 0, stream>>>(agg, W_fc, b_fc, out, N);
}

// Round 2
// 3446.613 us; speedup vs baseline: 4.9056x; 4.9056x over previous
//
#include <hip/hip_runtime.h>

#define TT 20
#define HH 64
#define NB 64      // nodes per block
#define HST 68     // padded LDS row stride (floats): 68*4B -> bank shift 16, conflict-free

__device__ __forceinline__ float fast_tanh(float a) {
    a = fminf(fmaxf(a, -12.0f), 12.0f);
    float e = __builtin_amdgcn_exp2f(a * 2.885390081777927f);
    return (e - 1.0f) * __builtin_amdgcn_rcpf(e + 1.0f);
}

__device__ __forceinline__ float f4get(const float4& v, int i) {
    return i == 0 ? v.x : (i == 1 ? v.y : (i == 2 ? v.z : v.w));
}

__global__ void k_dinit(float* __restrict__ deg, int N) {
    int n = blockIdx.x * blockDim.x + threadIdx.x;
    if (n < N) deg[n] = 1.0f;  // self-loop
}

__global__ void k_deg(const int* __restrict__ ei, float* __restrict__ deg, int E) {
    int e = blockIdx.x * blockDim.x + threadIdx.x;
    if (e < E) atomicAdd(&deg[ei[2 * e + 1]], 1.0f);
}

// Block = 256 threads, 64 nodes. h tile in LDS [64][68]; W^T in LDS [64][68].
// Thread (tj = t&15, tn = t>>4) computes nodes 4*tn..+3  x  outs 4*tj..+3.
__global__ __launch_bounds__(256, 2) void k_rnn(
    const float* __restrict__ x,
    const float* __restrict__ W_ih, const float* __restrict__ b_ih,
    const float* __restrict__ W_hh, const float* __restrict__ b_hh,
    const float* __restrict__ W_gcn, const float* __restrict__ b_gcn,
    const float* __restrict__ deg,
    float* __restrict__ xw, float* __restrict__ agg, int N)
{
    __shared__ float sH[NB * HST];
    __shared__ float sWT[HH * HST];
    __shared__ float sX[NB * TT];
    __shared__ float sWih[HH], sBsum[HH], sBgcn[HH];

    const int t  = threadIdx.x;
    const int tj = t & 15;
    const int tn = t >> 4;
    const int n0 = blockIdx.x * NB;

    // stage W_hh transposed: sWT[k][j] = W_hh[j][k]
    for (int i = t; i < HH * HH; i += 256) {
        int j = i >> 6, k = i & 63;
        sWT[k * HST + j] = W_hh[i];
    }
    // stage x rows for this block's nodes
    for (int i = t; i < NB * TT; i += 256) {
        int nn = i / TT, tt = i - nn * TT;
        int n = n0 + nn; if (n >= N) n = N - 1;
        sX[nn * TT + tt] = x[(size_t)n * TT + tt];
    }
    if (t < HH) {
        sWih[t]  = W_ih[t];
        sBsum[t] = b_ih[t] + b_hh[t];
        sBgcn[t] = b_gcn[t];
    }
    for (int i = t; i < NB * HST; i += 256) sH[i] = 0.0f;
    __syncthreads();

    float wih[4], bsum[4];
#pragma unroll
    for (int c = 0; c < 4; ++c) { wih[c] = sWih[4 * tj + c]; bsum[c] = sBsum[4 * tj + c]; }

    float acc[4][4];

    for (int step = 0; step < TT; ++step) {
#pragma unroll
        for (int r = 0; r < 4; ++r) {
            const float xt = sX[(4 * tn + r) * TT + step];
#pragma unroll
            for (int c = 0; c < 4; ++c) acc[r][c] = fmaf(xt, wih[c], bsum[c]);
        }
#pragma unroll
        for (int kq = 0; kq < HH / 4; ++kq) {
            float4 hf[4], wf[4];
#pragma unroll
            for (int r = 0; r < 4; ++r)
                hf[r] = *(const float4*)&sH[(4 * tn + r) * HST + 4 * kq];
#pragma unroll
            for (int q = 0; q < 4; ++q)
                wf[q] = *(const float4*)&sWT[(4 * kq + q) * HST + 4 * tj];
#pragma unroll
            for (int r = 0; r < 4; ++r) {
#pragma unroll
                for (int q = 0; q < 4; ++q) {
                    const float hv = f4get(hf[r], q);
#pragma unroll
                    for (int c = 0; c < 4; ++c)
                        acc[r][c] = fmaf(hv, f4get(wf[q], c), acc[r][c]);
                }
            }
        }
#pragma unroll
        for (int r = 0; r < 4; ++r)
#pragma unroll
            for (int c = 0; c < 4; ++c) acc[r][c] = fast_tanh(acc[r][c]);
        __syncthreads();   // everyone done reading sH
#pragma unroll
        for (int r = 0; r < 4; ++r) {
            float4 o; o.x = acc[r][0]; o.y = acc[r][1]; o.z = acc[r][2]; o.w = acc[r][3];
            *(float4*)&sH[(4 * tn + r) * HST + 4 * tj] = o;
        }
        __syncthreads();   // writes visible
    }

    // swap LDS weights to W_gcn^T
    for (int i = t; i < HH * HH; i += 256) {
        int j = i >> 6, k = i & 63;
        sWT[k * HST + j] = W_gcn[i];
    }
    __syncthreads();

    float g[4][4];
#pragma unroll
    for (int r = 0; r < 4; ++r)
#pragma unroll
        for (int c = 0; c < 4; ++c) g[r][c] = 0.0f;

#pragma unroll
    for (int kq = 0; kq < HH / 4; ++kq) {
        float4 hf[4], wf[4];
#pragma unroll
        for (int r = 0; r < 4; ++r)
            hf[r] = *(const float4*)&sH[(4 * tn + r) * HST + 4 * kq];
#pragma unroll
        for (int q = 0; q < 4; ++q)
            wf[q] = *(const float4*)&sWT[(4 * kq + q) * HST + 4 * tj];
#pragma unroll
        for (int r = 0; r < 4; ++r) {
#pragma unroll
            for (int q = 0; q < 4; ++q) {
                const float hv = f4get(hf[r], q);
#pragma unroll
                for (int c = 0; c < 4; ++c)
                    g[r][c] = fmaf(hv, f4get(wf[q], c), g[r][c]);
            }
        }
    }

    float bg[4];
#pragma unroll
    for (int c = 0; c < 4; ++c) bg[c] = sBgcn[4 * tj + c];

#pragma unroll
    for (int r = 0; r < 4; ++r) {
        const int n = n0 + 4 * tn + r;
        if (n < N) {
            const float invd = __builtin_amdgcn_rcpf(deg[n]);  // dinv^2 for self-loop
            float4 o; o.x = g[r][0]; o.y = g[r][1]; o.z = g[r][2]; o.w = g[r][3];
            *(float4*)&xw[(size_t)n * HH + 4 * tj] = o;
            float4 a;
            a.x = fmaf(g[r][0], invd, bg[0]);
            a.y = fmaf(g[r][1], invd, bg[1]);
            a.z = fmaf(g[r][2], invd, bg[2]);
            a.w = fmaf(g[r][3], invd, bg[3]);
            *(float4*)&agg[(size_t)n * HH + 4 * tj] = a;
        }
    }
}

__global__ void k_scatter(const int* __restrict__ ei, const float* __restrict__ deg,
                          const float* __restrict__ xw, float* __restrict__ agg, int E)
{
    int gid = blockIdx.x * blockDim.x + threadIdx.x;
    int e = gid >> 4;
    int l = gid & 15;
    if (e >= E) return;
    int s = ei[2 * e + 0];
    int d = ei[2 * e + 1];
    float norm = __frsqrt_rn(deg[s]) * __frsqrt_rn(deg[d]);
    const float4 v = *(const float4*)(xw + (size_t)s * HH + l * 4);
    float* ap = agg + (size_t)d * HH + l * 4;
    atomicAdd(ap + 0, v.x * norm);
    atomicAdd(ap + 1, v.y * norm);
    atomicAdd(ap + 2, v.z * norm);
    atomicAdd(ap + 3, v.w * norm);
}

__global__ void k_out(const float* __restrict__ agg, const float* __restrict__ Wfc,
                      const float* __restrict__ bfc, float* __restrict__ out, int N)
{
    __shared__ float sw[HH];
    if (threadIdx.x < HH) sw[threadIdx.x] = Wfc[threadIdx.x];
    __syncthreads();
    int n = blockIdx.x * blockDim.x + threadIdx.x;
    if (n >= N) return;
    const float4* ap = (const float4*)(agg + (size_t)n * HH);
    float acc = bfc[0];
#pragma unroll
    for (int k = 0; k < HH / 4; ++k) {
        float4 a = ap[k];
        acc = fmaf(a.x, sw[4 * k + 0], acc);
        acc = fmaf(a.y, sw[4 * k + 1], acc);
        acc = fmaf(a.z, sw[4 * k + 2], acc);
        acc = fmaf(a.w, sw[4 * k + 3], acc);
    }
    out[n] = acc;
}

extern "C" void kernel_launch(void* const* d_in, const int* in_sizes, int n_in,
                              void* d_out, int out_size, void* d_ws, size_t ws_size,
                              hipStream_t stream)
{
    const float* x     = (const float*)d_in[0];
    const int*   ei    = (const int*)d_in[1];
    const float* W_ih  = (const float*)d_in[2];
    const float* b_ih  = (const float*)d_in[3];
    const float* W_hh  = (const float*)d_in[4];
    const float* b_hh  = (const float*)d_in[5];
    const float* W_gcn = (const float*)d_in[6];
    const float* b_gcn = (const float*)d_in[7];
    const float* W_fc  = (const float*)d_in[8];
    const float* b_fc  = (const float*)d_in[9];
    float* out = (float*)d_out;

    const int N = in_sizes[0] / TT;
    const int E = in_sizes[1] / 2;

    char* ws = (char*)d_ws;
    float* deg = (float*)ws;                                      // N floats
    size_t xw_off  = (size_t)1 << 20;                             // 1 MB
    size_t xw_sz   = (size_t)N * HH * sizeof(float);
    size_t agg_off = xw_off + ((xw_sz + 1023) / 1024) * 1024;
    float* xw  = (float*)(ws + xw_off);
    float* agg = (float*)(ws + agg_off);

    k_dinit<<<(N + 255) / 256, 256, 0, stream>>>(deg, N);
    k_deg<<<(E + 255) / 256, 256, 0, stream>>>(ei, deg, E);
    k_rnn<<<(N + NB - 1) / NB, 256, 0, stream>>>(x, W_ih, b_ih, W_hh, b_hh,
                                                 W_gcn, b_gcn, deg, xw, agg, N);
    long long tot = (long long)E * 16;
    k_scatter<<<(int)((tot + 255) / 256), 256, 0, stream>>>(ei, deg, xw, agg, E);
    k_out<<<(N + 255) / 256, 256, 0, stream>>>(agg, W_fc, b_fc, out, N);
}

// Round 3
// 1093.413 us; speedup vs baseline: 15.4634x; 3.1522x over previous
//
#include <hip/hip_runtime.h>

#define TT 20
#define HH 64
#define NB 64      // nodes per block in k_rnn
#define HST 68     // padded LDS row stride

__device__ __forceinline__ float fast_tanh(float a) {
    a = fminf(fmaxf(a, -12.0f), 12.0f);
    float e = __builtin_amdgcn_exp2f(a * 2.885390081777927f);
    return (e - 1.0f) * __builtin_amdgcn_rcpf(e + 1.0f);
}

__device__ __forceinline__ float f4get(const float4& v, int i) {
    return i == 0 ? v.x : (i == 1 ? v.y : (i == 2 ? v.z : v.w));
}

// ---------------- CSR build ----------------

__global__ void k_hist(const int* __restrict__ ei, int* __restrict__ cnt, int E) {
    int e = blockIdx.x * blockDim.x + threadIdx.x;
    if (e < E) atomicAdd(&cnt[ei[2 * e + 1]], 1);
}

// scan pass 1: per-block (1024 elems) local exclusive scan + block totals
__global__ __launch_bounds__(256) void k_scan1(const int* __restrict__ cnt,
                                               int* __restrict__ part,
                                               int* __restrict__ bsum, int N) {
    __shared__ int ss[256];
    const int t = threadIdx.x;
    const int base = blockIdx.x * 1024 + t * 4;
    int v[4];
#pragma unroll
    for (int i = 0; i < 4; ++i) v[i] = (base + i < N) ? cnt[base + i] : 0;
    int s = v[0] + v[1] + v[2] + v[3];
    ss[t] = s;
    __syncthreads();
    for (int st = 1; st < 256; st <<= 1) {
        int add = (t >= st) ? ss[t - st] : 0;
        __syncthreads();
        ss[t] += add;
        __syncthreads();
    }
    int excl = t ? ss[t - 1] : 0;
    int run = excl;
#pragma unroll
    for (int i = 0; i < 4; ++i) {
        if (base + i < N) part[base + i] = run;
        run += v[i];
    }
    if (t == 255) bsum[blockIdx.x] = ss[255];
}

// scan pass 2: single block scans the (<=256) block sums, in-place exclusive
__global__ __launch_bounds__(256) void k_scan2(int* __restrict__ bsum, int nblk) {
    __shared__ int ss[256];
    const int t = threadIdx.x;
    int v = (t < nblk) ? bsum[t] : 0;
    ss[t] = v;
    __syncthreads();
    for (int st = 1; st < 256; st <<= 1) {
        int add = (t >= st) ? ss[t - st] : 0;
        __syncthreads();
        ss[t] += add;
        __syncthreads();
    }
    int excl = t ? ss[t - 1] : 0;
    if (t < nblk) bsum[t] = excl;
}

// scan pass 3: finalize offsets + cursor + dinv
__global__ __launch_bounds__(256) void k_scan3(const int* __restrict__ part,
                                               const int* __restrict__ bsum,
                                               const int* __restrict__ cnt,
                                               int* __restrict__ offsets,
                                               int* __restrict__ cursor,
                                               float* __restrict__ dinv, int N) {
    const int base = blockIdx.x * 1024 + threadIdx.x * 4;
    const int boff = bsum[blockIdx.x];
#pragma unroll
    for (int i = 0; i < 4; ++i) {
        int n = base + i;
        if (n < N) {
            int off = part[n] + boff;
            offsets[n] = off;
            cursor[n]  = off;
            dinv[n] = __frsqrt_rn((float)(cnt[n] + 1));  // +1 self-loop
        }
    }
}

__global__ void k_fill(const int* __restrict__ ei, int* __restrict__ cursor,
                       int* __restrict__ srcs, int E) {
    int e = blockIdx.x * blockDim.x + threadIdx.x;
    if (e >= E) return;
    int s = ei[2 * e + 0];
    int d = ei[2 * e + 1];
    int pos = atomicAdd(&cursor[d], 1);
    srcs[pos] = s;
}

// ---------------- RNN + self-loop GCN term ----------------

__global__ __launch_bounds__(256, 2) void k_rnn(
    const float* __restrict__ x,
    const float* __restrict__ W_ih, const float* __restrict__ b_ih,
    const float* __restrict__ W_hh, const float* __restrict__ b_hh,
    const float* __restrict__ W_gcn, const float* __restrict__ b_gcn,
    const float* __restrict__ dinv,
    float* __restrict__ xw, float* __restrict__ agg, int N)
{
    __shared__ float sH[NB * HST];
    __shared__ float sWT[HH * HST];
    __shared__ float sX[NB * TT];
    __shared__ float sWih[HH], sBsum[HH], sBgcn[HH];

    const int t  = threadIdx.x;
    const int tj = t & 15;
    const int tn = t >> 4;
    const int n0 = blockIdx.x * NB;

    for (int i = t; i < HH * HH; i += 256) {
        int j = i >> 6, k = i & 63;
        sWT[k * HST + j] = W_hh[i];
    }
    for (int i = t; i < NB * TT; i += 256) {
        int nn = i / TT, tt = i - nn * TT;
        int n = n0 + nn; if (n >= N) n = N - 1;
        sX[nn * TT + tt] = x[(size_t)n * TT + tt];
    }
    if (t < HH) {
        sWih[t]  = W_ih[t];
        sBsum[t] = b_ih[t] + b_hh[t];
        sBgcn[t] = b_gcn[t];
    }
    for (int i = t; i < NB * HST; i += 256) sH[i] = 0.0f;
    __syncthreads();

    float wih[4], bsum[4];
#pragma unroll
    for (int c = 0; c < 4; ++c) { wih[c] = sWih[4 * tj + c]; bsum[c] = sBsum[4 * tj + c]; }

    float acc[4][4];

    for (int step = 0; step < TT; ++step) {
#pragma unroll
        for (int r = 0; r < 4; ++r) {
            const float xt = sX[(4 * tn + r) * TT + step];
#pragma unroll
            for (int c = 0; c < 4; ++c) acc[r][c] = fmaf(xt, wih[c], bsum[c]);
        }
#pragma unroll
        for (int kq = 0; kq < HH / 4; ++kq) {
            float4 hf[4], wf[4];
#pragma unroll
            for (int r = 0; r < 4; ++r)
                hf[r] = *(const float4*)&sH[(4 * tn + r) * HST + 4 * kq];
#pragma unroll
            for (int q = 0; q < 4; ++q)
                wf[q] = *(const float4*)&sWT[(4 * kq + q) * HST + 4 * tj];
#pragma unroll
            for (int r = 0; r < 4; ++r) {
#pragma unroll
                for (int q = 0; q < 4; ++q) {
                    const float hv = f4get(hf[r], q);
#pragma unroll
                    for (int c = 0; c < 4; ++c)
                        acc[r][c] = fmaf(hv, f4get(wf[q], c), acc[r][c]);
                }
            }
        }
#pragma unroll
        for (int r = 0; r < 4; ++r)
#pragma unroll
            for (int c = 0; c < 4; ++c) acc[r][c] = fast_tanh(acc[r][c]);
        __syncthreads();
#pragma unroll
        for (int r = 0; r < 4; ++r) {
            float4 o; o.x = acc[r][0]; o.y = acc[r][1]; o.z = acc[r][2]; o.w = acc[r][3];
            *(float4*)&sH[(4 * tn + r) * HST + 4 * tj] = o;
        }
        __syncthreads();
    }

    for (int i = t; i < HH * HH; i += 256) {
        int j = i >> 6, k = i & 63;
        sWT[k * HST + j] = W_gcn[i];
    }
    __syncthreads();

    float g[4][4];
#pragma unroll
    for (int r = 0; r < 4; ++r)
#pragma unroll
        for (int c = 0; c < 4; ++c) g[r][c] = 0.0f;

#pragma unroll
    for (int kq = 0; kq < HH / 4; ++kq) {
        float4 hf[4], wf[4];
#pragma unroll
        for (int r = 0; r < 4; ++r)
            hf[r] = *(const float4*)&sH[(4 * tn + r) * HST + 4 * kq];
#pragma unroll
        for (int q = 0; q < 4; ++q)
            wf[q] = *(const float4*)&sWT[(4 * kq + q) * HST + 4 * tj];
#pragma unroll
        for (int r = 0; r < 4; ++r) {
#pragma unroll
            for (int q = 0; q < 4; ++q) {
                const float hv = f4get(hf[r], q);
#pragma unroll
                for (int c = 0; c < 4; ++c)
                    g[r][c] = fmaf(hv, f4get(wf[q], c), g[r][c]);
            }
        }
    }

    float bg[4];
#pragma unroll
    for (int c = 0; c < 4; ++c) bg[c] = sBgcn[4 * tj + c];

#pragma unroll
    for (int r = 0; r < 4; ++r) {
        const int n = n0 + 4 * tn + r;
        if (n < N) {
            const float dn = dinv[n];
            const float invd = dn * dn;   // self-loop norm
            float4 o; o.x = g[r][0]; o.y = g[r][1]; o.z = g[r][2]; o.w = g[r][3];
            *(float4*)&xw[(size_t)n * HH + 4 * tj] = o;
            float4 a;
            a.x = fmaf(g[r][0], invd, bg[0]);
            a.y = fmaf(g[r][1], invd, bg[1]);
            a.z = fmaf(g[r][2], invd, bg[2]);
            a.w = fmaf(g[r][3], invd, bg[3]);
            *(float4*)&agg[(size_t)n * HH + 4 * tj] = a;
        }
    }
}

// ---------------- pull-mode aggregation (no fp atomics) ----------------

__global__ __launch_bounds__(256) void k_gather(
    const int* __restrict__ offsets, const int* __restrict__ cnt,
    const int* __restrict__ srcs, const float* __restrict__ dinv,
    const float* __restrict__ xw, float* __restrict__ agg, int N)
{
    int gid = blockIdx.x * blockDim.x + threadIdx.x;
    int d = gid >> 4;
    int l = gid & 15;
    if (d >= N) return;
    const int beg = offsets[d];
    const int num = cnt[d];
    const float dn = dinv[d];

    float4 acc = *(const float4*)&agg[(size_t)d * HH + l * 4];

    int sCur = 0; float dsCur = 0.0f;
    if (num > 0) { sCur = srcs[beg]; dsCur = dinv[sCur]; }
    for (int i = 0; i < num; ++i) {
        const int s = sCur;
        const float nrm = dn * dsCur;
        if (i + 1 < num) { sCur = srcs[beg + i + 1]; dsCur = dinv[sCur]; }
        const float4 v = *(const float4*)&xw[(size_t)s * HH + l * 4];
        acc.x = fmaf(v.x, nrm, acc.x);
        acc.y = fmaf(v.y, nrm, acc.y);
        acc.z = fmaf(v.z, nrm, acc.z);
        acc.w = fmaf(v.w, nrm, acc.w);
    }
    *(float4*)&agg[(size_t)d * HH + l * 4] = acc;
}

__global__ void k_out(const float* __restrict__ agg, const float* __restrict__ Wfc,
                      const float* __restrict__ bfc, float* __restrict__ out, int N)
{
    __shared__ float sw[HH];
    if (threadIdx.x < HH) sw[threadIdx.x] = Wfc[threadIdx.x];
    __syncthreads();
    int n = blockIdx.x * blockDim.x + threadIdx.x;
    if (n >= N) return;
    const float4* ap = (const float4*)(agg + (size_t)n * HH);
    float acc = bfc[0];
#pragma unroll
    for (int k = 0; k < HH / 4; ++k) {
        float4 a = ap[k];
        acc = fmaf(a.x, sw[4 * k + 0], acc);
        acc = fmaf(a.y, sw[4 * k + 1], acc);
        acc = fmaf(a.z, sw[4 * k + 2], acc);
        acc = fmaf(a.w, sw[4 * k + 3], acc);
    }
    out[n] = acc;
}

extern "C" void kernel_launch(void* const* d_in, const int* in_sizes, int n_in,
                              void* d_out, int out_size, void* d_ws, size_t ws_size,
                              hipStream_t stream)
{
    const float* x     = (const float*)d_in[0];
    const int*   ei    = (const int*)d_in[1];
    const float* W_ih  = (const float*)d_in[2];
    const float* b_ih  = (const float*)d_in[3];
    const float* W_hh  = (const float*)d_in[4];
    const float* b_hh  = (const float*)d_in[5];
    const float* W_gcn = (const float*)d_in[6];
    const float* b_gcn = (const float*)d_in[7];
    const float* W_fc  = (const float*)d_in[8];
    const float* b_fc  = (const float*)d_in[9];
    float* out = (float*)d_out;

    const int N = in_sizes[0] / TT;
    const int E = in_sizes[1] / 2;
    const int nblk = (N + 1023) / 1024;

    // workspace layout
    char* ws = (char*)d_ws;
    size_t off = 0;
    auto alloc = [&](size_t bytes) { void* p = ws + off; off += (bytes + 255) & ~(size_t)255; return p; };
    int*   cnt     = (int*)  alloc((size_t)N * 4);
    int*   part    = (int*)  alloc((size_t)N * 4);
    int*   bsum    = (int*)  alloc(4096);
    int*   offsets = (int*)  alloc((size_t)N * 4);
    int*   cursor  = (int*)  alloc((size_t)N * 4);
    float* dinv    = (float*)alloc((size_t)N * 4);
    int*   srcs    = (int*)  alloc((size_t)E * 4);
    float* xw      = (float*)alloc((size_t)N * HH * 4);
    float* agg     = (float*)alloc((size_t)N * HH * 4);

    hipMemsetAsync(cnt, 0, (size_t)N * 4, stream);

    k_hist <<<(E + 255) / 256, 256, 0, stream>>>(ei, cnt, E);
    k_scan1<<<nblk, 256, 0, stream>>>(cnt, part, bsum, N);
    k_scan2<<<1, 256, 0, stream>>>(bsum, nblk);
    k_scan3<<<nblk, 256, 0, stream>>>(part, bsum, cnt, offsets, cursor, dinv, N);
    k_fill <<<(E + 255) / 256, 256, 0, stream>>>(ei, cursor, srcs, E);
    k_rnn  <<<(N + NB - 1) / NB, 256, 0, stream>>>(x, W_ih, b_ih, W_hh, b_hh,
                                                   W_gcn, b_gcn, dinv, xw, agg, N);
    k_gather<<<((N * 16) + 255) / 256, 256, 0, stream>>>(offsets, cnt, srcs, dinv, xw, agg, N);
    k_out  <<<(N + 255) / 256, 256, 0, stream>>>(agg, W_fc, b_fc, out, N);
}

// Round 4
// 866.492 us; speedup vs baseline: 19.5130x; 1.2619x over previous
//
#include <hip/hip_runtime.h>

#define TT 20
#define HH 64
#define NB 64      // nodes per block in k_rnn
#define HST 68     // padded LDS row stride

__device__ __forceinline__ float fast_tanh(float a) {
    a = fminf(fmaxf(a, -12.0f), 12.0f);
    float e = __builtin_amdgcn_exp2f(a * 2.885390081777927f);
    return (e - 1.0f) * __builtin_amdgcn_rcpf(e + 1.0f);
}

__device__ __forceinline__ float f4get(const float4& v, int i) {
    return i == 0 ? v.x : (i == 1 ? v.y : (i == 2 ? v.z : v.w));
}

// ---------------- CSR build ----------------

__global__ void k_hist(const int* __restrict__ ei, int* __restrict__ cnt, int E) {
    int e = blockIdx.x * blockDim.x + threadIdx.x;
    if (e < E) atomicAdd(&cnt[ei[2 * e + 1]], 1);
}

__global__ __launch_bounds__(256) void k_scan1(const int* __restrict__ cnt,
                                               int* __restrict__ part,
                                               int* __restrict__ bsum, int N) {
    __shared__ int ss[256];
    const int t = threadIdx.x;
    const int base = blockIdx.x * 1024 + t * 4;
    int v[4];
#pragma unroll
    for (int i = 0; i < 4; ++i) v[i] = (base + i < N) ? cnt[base + i] : 0;
    int s = v[0] + v[1] + v[2] + v[3];
    ss[t] = s;
    __syncthreads();
    for (int st = 1; st < 256; st <<= 1) {
        int add = (t >= st) ? ss[t - st] : 0;
        __syncthreads();
        ss[t] += add;
        __syncthreads();
    }
    int excl = t ? ss[t - 1] : 0;
    int run = excl;
#pragma unroll
    for (int i = 0; i < 4; ++i) {
        if (base + i < N) part[base + i] = run;
        run += v[i];
    }
    if (t == 255) bsum[blockIdx.x] = ss[255];
}

__global__ __launch_bounds__(256) void k_scan2(int* __restrict__ bsum, int nblk) {
    __shared__ int ss[256];
    const int t = threadIdx.x;
    int v = (t < nblk) ? bsum[t] : 0;
    ss[t] = v;
    __syncthreads();
    for (int st = 1; st < 256; st <<= 1) {
        int add = (t >= st) ? ss[t - st] : 0;
        __syncthreads();
        ss[t] += add;
        __syncthreads();
    }
    int excl = t ? ss[t - 1] : 0;
    if (t < nblk) bsum[t] = excl;
}

__global__ __launch_bounds__(256) void k_scan3(const int* __restrict__ part,
                                               const int* __restrict__ bsum,
                                               const int* __restrict__ cnt,
                                               int* __restrict__ offsets,
                                               int* __restrict__ cursor,
                                               float* __restrict__ dinv, int N) {
    const int base = blockIdx.x * 1024 + threadIdx.x * 4;
    const int boff = bsum[blockIdx.x];
#pragma unroll
    for (int i = 0; i < 4; ++i) {
        int n = base + i;
        if (n < N) {
            int off = part[n] + boff;
            offsets[n] = off;
            cursor[n]  = off;
            dinv[n] = __frsqrt_rn((float)(cnt[n] + 1));  // +1 self-loop
        }
    }
}

__global__ void k_fill(const int* __restrict__ ei, int* __restrict__ cursor,
                       int* __restrict__ srcs, int E) {
    int e = blockIdx.x * blockDim.x + threadIdx.x;
    if (e >= E) return;
    int s = ei[2 * e + 0];
    int d = ei[2 * e + 1];
    int pos = atomicAdd(&cursor[d], 1);
    srcs[pos] = s;
}

// ---------------- RNN + self-loop GCN term ----------------

__global__ __launch_bounds__(256) void k_rnn(
    const float* __restrict__ x,
    const float* __restrict__ W_ih, const float* __restrict__ b_ih,
    const float* __restrict__ W_hh, const float* __restrict__ b_hh,
    const float* __restrict__ W_gcn, const float* __restrict__ b_gcn,
    const float* __restrict__ dinv,
    float* __restrict__ xw, float* __restrict__ agg, int N)
{
    __shared__ float sH[NB * HST];
    __shared__ float sWT[HH * HST];
    __shared__ float sX[NB * TT];
    __shared__ float sWih[HH], sBsum[HH], sBgcn[HH];

    const int t  = threadIdx.x;
    const int tj = t & 15;
    const int tn = t >> 4;
    const int n0 = blockIdx.x * NB;

    for (int i = t; i < HH * HH; i += 256) {
        int j = i >> 6, k = i & 63;
        sWT[k * HST + j] = W_hh[i];
    }
    for (int i = t; i < NB * TT; i += 256) {
        int nn = i / TT, tt = i - nn * TT;
        int n = n0 + nn; if (n >= N) n = N - 1;
        sX[nn * TT + tt] = x[(size_t)n * TT + tt];
    }
    if (t < HH) {
        sWih[t]  = W_ih[t];
        sBsum[t] = b_ih[t] + b_hh[t];
        sBgcn[t] = b_gcn[t];
    }
    for (int i = t; i < NB * HST; i += 256) sH[i] = 0.0f;
    __syncthreads();

    float wih[4], bsum[4];
#pragma unroll
    for (int c = 0; c < 4; ++c) { wih[c] = sWih[4 * tj + c]; bsum[c] = sBsum[4 * tj + c]; }

    float acc[4][4];

    for (int step = 0; step < TT; ++step) {
#pragma unroll
        for (int r = 0; r < 4; ++r) {
            const float xt = sX[(4 * tn + r) * TT + step];
#pragma unroll
            for (int c = 0; c < 4; ++c) acc[r][c] = fmaf(xt, wih[c], bsum[c]);
        }
        // small unroll window: keeps live set ~70 VGPRs, no spill
#pragma unroll 2
        for (int kq = 0; kq < HH / 4; ++kq) {
            float4 hf[4];
#pragma unroll
            for (int r = 0; r < 4; ++r)
                hf[r] = *(const float4*)&sH[(4 * tn + r) * HST + 4 * kq];
#pragma unroll
            for (int q = 0; q < 4; ++q) {
                const float4 w = *(const float4*)&sWT[(4 * kq + q) * HST + 4 * tj];
#pragma unroll
                for (int r = 0; r < 4; ++r) {
                    const float hv = f4get(hf[r], q);
                    acc[r][0] = fmaf(hv, w.x, acc[r][0]);
                    acc[r][1] = fmaf(hv, w.y, acc[r][1]);
                    acc[r][2] = fmaf(hv, w.z, acc[r][2]);
                    acc[r][3] = fmaf(hv, w.w, acc[r][3]);
                }
            }
        }
#pragma unroll
        for (int r = 0; r < 4; ++r)
#pragma unroll
            for (int c = 0; c < 4; ++c) acc[r][c] = fast_tanh(acc[r][c]);
        __syncthreads();
#pragma unroll
        for (int r = 0; r < 4; ++r) {
            float4 o; o.x = acc[r][0]; o.y = acc[r][1]; o.z = acc[r][2]; o.w = acc[r][3];
            *(float4*)&sH[(4 * tn + r) * HST + 4 * tj] = o;
        }
        __syncthreads();
    }

    for (int i = t; i < HH * HH; i += 256) {
        int j = i >> 6, k = i & 63;
        sWT[k * HST + j] = W_gcn[i];
    }
    __syncthreads();

    float g[4][4];
#pragma unroll
    for (int r = 0; r < 4; ++r)
#pragma unroll
        for (int c = 0; c < 4; ++c) g[r][c] = 0.0f;

#pragma unroll 2
    for (int kq = 0; kq < HH / 4; ++kq) {
        float4 hf[4];
#pragma unroll
        for (int r = 0; r < 4; ++r)
            hf[r] = *(const float4*)&sH[(4 * tn + r) * HST + 4 * kq];
#pragma unroll
        for (int q = 0; q < 4; ++q) {
            const float4 w = *(const float4*)&sWT[(4 * kq + q) * HST + 4 * tj];
#pragma unroll
            for (int r = 0; r < 4; ++r) {
                const float hv = f4get(hf[r], q);
                g[r][0] = fmaf(hv, w.x, g[r][0]);
                g[r][1] = fmaf(hv, w.y, g[r][1]);
                g[r][2] = fmaf(hv, w.z, g[r][2]);
                g[r][3] = fmaf(hv, w.w, g[r][3]);
            }
        }
    }

    float bg[4];
#pragma unroll
    for (int c = 0; c < 4; ++c) bg[c] = sBgcn[4 * tj + c];

#pragma unroll
    for (int r = 0; r < 4; ++r) {
        const int n = n0 + 4 * tn + r;
        if (n < N) {
            const float dn = dinv[n];
            const float invd = dn * dn;   // self-loop norm
            float4 o; o.x = g[r][0]; o.y = g[r][1]; o.z = g[r][2]; o.w = g[r][3];
            *(float4*)&xw[(size_t)n * HH + 4 * tj] = o;
            float4 a;
            a.x = fmaf(g[r][0], invd, bg[0]);
            a.y = fmaf(g[r][1], invd, bg[1]);
            a.z = fmaf(g[r][2], invd, bg[2]);
            a.w = fmaf(g[r][3], invd, bg[3]);
            *(float4*)&agg[(size_t)n * HH + 4 * tj] = a;
        }
    }
}

// ---------------- pull-mode aggregation (no fp atomics) ----------------

__global__ __launch_bounds__(256) void k_gather(
    const int* __restrict__ offsets, const int* __restrict__ cnt,
    const int* __restrict__ srcs, const float* __restrict__ dinv,
    const float* __restrict__ xw, float* __restrict__ agg, int N)
{
    int gid = blockIdx.x * blockDim.x + threadIdx.x;
    int d = gid >> 4;
    int l = gid & 15;
    if (d >= N) return;
    const int beg = offsets[d];
    const int num = cnt[d];
    const float dn = dinv[d];

    float4 acc = *(const float4*)&agg[(size_t)d * HH + l * 4];

    int sCur = 0; float dsCur = 0.0f;
    if (num > 0) { sCur = srcs[beg]; dsCur = dinv[sCur]; }
    for (int i = 0; i < num; ++i) {
        const int s = sCur;
        const float nrm = dn * dsCur;
        if (i + 1 < num) { sCur = srcs[beg + i + 1]; dsCur = dinv[sCur]; }
        const float4 v = *(const float4*)&xw[(size_t)s * HH + l * 4];
        acc.x = fmaf(v.x, nrm, acc.x);
        acc.y = fmaf(v.y, nrm, acc.y);
        acc.z = fmaf(v.z, nrm, acc.z);
        acc.w = fmaf(v.w, nrm, acc.w);
    }
    *(float4*)&agg[(size_t)d * HH + l * 4] = acc;
}

__global__ void k_out(const float* __restrict__ agg, const float* __restrict__ Wfc,
                      const float* __restrict__ bfc, float* __restrict__ out, int N)
{
    __shared__ float sw[HH];
    if (threadIdx.x < HH) sw[threadIdx.x] = Wfc[threadIdx.x];
    __syncthreads();
    int n = blockIdx.x * blockDim.x + threadIdx.x;
    if (n >= N) return;
    const float4* ap = (const float4*)(agg + (size_t)n * HH);
    float acc = bfc[0];
#pragma unroll
    for (int k = 0; k < HH / 4; ++k) {
        float4 a = ap[k];
        acc = fmaf(a.x, sw[4 * k + 0], acc);
        acc = fmaf(a.y, sw[4 * k + 1], acc);
        acc = fmaf(a.z, sw[4 * k + 2], acc);
        acc = fmaf(a.w, sw[4 * k + 3], acc);
    }
    out[n] = acc;
}

extern "C" void kernel_launch(void* const* d_in, const int* in_sizes, int n_in,
                              void* d_out, int out_size, void* d_ws, size_t ws_size,
                              hipStream_t stream)
{
    const float* x     = (const float*)d_in[0];
    const int*   ei    = (const int*)d_in[1];
    const float* W_ih  = (const float*)d_in[2];
    const float* b_ih  = (const float*)d_in[3];
    const float* W_hh  = (const float*)d_in[4];
    const float* b_hh  = (const float*)d_in[5];
    const float* W_gcn = (const float*)d_in[6];
    const float* b_gcn = (const float*)d_in[7];
    const float* W_fc  = (const float*)d_in[8];
    const float* b_fc  = (const float*)d_in[9];
    float* out = (float*)d_out;

    const int N = in_sizes[0] / TT;
    const int E = in_sizes[1] / 2;
    const int nblk = (N + 1023) / 1024;

    char* ws = (char*)d_ws;
    size_t off = 0;
    auto alloc = [&](size_t bytes) { void* p = ws + off; off += (bytes + 255) & ~(size_t)255; return p; };
    int*   cnt     = (int*)  alloc((size_t)N * 4);
    int*   part    = (int*)  alloc((size_t)N * 4);
    int*   bsum    = (int*)  alloc(4096);
    int*   offsets = (int*)  alloc((size_t)N * 4);
    int*   cursor  = (int*)  alloc((size_t)N * 4);
    float* dinv    = (float*)alloc((size_t)N * 4);
    int*   srcs    = (int*)  alloc((size_t)E * 4);
    float* xw      = (float*)alloc((size_t)N * HH * 4);
    float* agg     = (float*)alloc((size_t)N * HH * 4);

    hipMemsetAsync(cnt, 0, (size_t)N * 4, stream);

    k_hist <<<(E + 255) / 256, 256, 0, stream>>>(ei, cnt, E);
    k_scan1<<<nblk, 256, 0, stream>>>(cnt, part, bsum, N);
    k_scan2<<<1, 256, 0, stream>>>(bsum, nblk);
    k_scan3<<<nblk, 256, 0, stream>>>(part, bsum, cnt, offsets, cursor, dinv, N);
    k_fill <<<(E + 255) / 256, 256, 0, stream>>>(ei, cursor, srcs, E);
    k_rnn  <<<(N + NB - 1) / NB, 256, 0, stream>>>(x, W_ih, b_ih, W_hh, b_hh,
                                                   W_gcn, b_gcn, dinv, xw, agg, N);
    k_gather<<<((N * 16) + 255) / 256, 256, 0, stream>>>(offsets, cnt, srcs, dinv, xw, agg, N);
    k_out  <<<(N + 255) / 256, 256, 0, stream>>>(agg, W_fc, b_fc, out, N);
}

// Round 5
// 663.360 us; speedup vs baseline: 25.4882x; 1.3062x over previous
//
#include <hip/hip_runtime.h>

#define TT 20
#define HH 64
#define NB 64      // nodes per block in k_rnn
#define HST 68     // padded LDS row stride

__device__ __forceinline__ float fast_tanh(float a) {
    a = fminf(fmaxf(a, -12.0f), 12.0f);
    float e = __builtin_amdgcn_exp2f(a * 2.885390081777927f);
    return (e - 1.0f) * __builtin_amdgcn_rcpf(e + 1.0f);
}

__device__ __forceinline__ float f4get(const float4& v, int i) {
    return i == 0 ? v.x : (i == 1 ? v.y : (i == 2 ? v.z : v.w));
}

// deg=1 (self-loop), S=0
__global__ void k_dinit(float* __restrict__ deg, float* __restrict__ S, int N) {
    int n = blockIdx.x * blockDim.x + threadIdx.x;
    if (n < N) { deg[n] = 1.0f; S[n] = 0.0f; }
}

__global__ void k_deg(const int* __restrict__ ei, float* __restrict__ deg, int E) {
    int e = blockIdx.x * blockDim.x + threadIdx.x;
    if (e < E) atomicAdd(&deg[ei[2 * e + 1]], 1.0f);
}

// v = W_gcn^T w_fc  (64 floats), c = w_fc . b_gcn + b_fc
__global__ __launch_bounds__(64) void k_prep(const float* __restrict__ W_gcn,
                                             const float* __restrict__ b_gcn,
                                             const float* __restrict__ W_fc,
                                             const float* __restrict__ b_fc,
                                             float* __restrict__ v, float* __restrict__ c) {
    __shared__ float sw[HH];
    const int k = threadIdx.x;
    sw[k] = W_fc[k];
    __syncthreads();
    float acc = 0.0f;
#pragma unroll 8
    for (int j = 0; j < HH; ++j) acc = fmaf(sw[j], W_gcn[j * HH + k], acc);
    v[k] = acc;
    if (k == 0) {
        float cc = b_fc[0];
        for (int j = 0; j < HH; ++j) cc = fmaf(sw[j], b_gcn[j], cc);
        *c = cc;
    }
}

// RNN over 20 steps; epilogue: z[n] = h_n . v  (scalar per node)
__global__ __launch_bounds__(256) void k_rnn(
    const float* __restrict__ x,
    const float* __restrict__ W_ih, const float* __restrict__ b_ih,
    const float* __restrict__ W_hh, const float* __restrict__ b_hh,
    const float* __restrict__ v,
    float* __restrict__ z, int N)
{
    __shared__ float sH[NB * HST];
    __shared__ float sWT[HH * HST];
    __shared__ float sX[NB * TT];
    __shared__ float sWih[HH], sBsum[HH], sV[HH];

    const int t  = threadIdx.x;
    const int tj = t & 15;
    const int tn = t >> 4;
    const int n0 = blockIdx.x * NB;

    for (int i = t; i < HH * HH; i += 256) {
        int j = i >> 6, k = i & 63;
        sWT[k * HST + j] = W_hh[i];
    }
    for (int i = t; i < NB * TT; i += 256) {
        int nn = i / TT, tt = i - nn * TT;
        int n = n0 + nn; if (n >= N) n = N - 1;
        sX[nn * TT + tt] = x[(size_t)n * TT + tt];
    }
    if (t < HH) {
        sWih[t]  = W_ih[t];
        sBsum[t] = b_ih[t] + b_hh[t];
        sV[t]    = v[t];
    }
    for (int i = t; i < NB * HST; i += 256) sH[i] = 0.0f;
    __syncthreads();

    float wih[4], bsum[4];
#pragma unroll
    for (int c = 0; c < 4; ++c) { wih[c] = sWih[4 * tj + c]; bsum[c] = sBsum[4 * tj + c]; }

    float acc[4][4];

    for (int step = 0; step < TT; ++step) {
#pragma unroll
        for (int r = 0; r < 4; ++r) {
            const float xt = sX[(4 * tn + r) * TT + step];
#pragma unroll
            for (int c = 0; c < 4; ++c) acc[r][c] = fmaf(xt, wih[c], bsum[c]);
        }
#pragma unroll 2
        for (int kq = 0; kq < HH / 4; ++kq) {
            float4 hf[4];
#pragma unroll
            for (int r = 0; r < 4; ++r)
                hf[r] = *(const float4*)&sH[(4 * tn + r) * HST + 4 * kq];
#pragma unroll
            for (int q = 0; q < 4; ++q) {
                const float4 w = *(const float4*)&sWT[(4 * kq + q) * HST + 4 * tj];
#pragma unroll
                for (int r = 0; r < 4; ++r) {
                    const float hv = f4get(hf[r], q);
                    acc[r][0] = fmaf(hv, w.x, acc[r][0]);
                    acc[r][1] = fmaf(hv, w.y, acc[r][1]);
                    acc[r][2] = fmaf(hv, w.z, acc[r][2]);
                    acc[r][3] = fmaf(hv, w.w, acc[r][3]);
                }
            }
        }
#pragma unroll
        for (int r = 0; r < 4; ++r)
#pragma unroll
            for (int c = 0; c < 4; ++c) acc[r][c] = fast_tanh(acc[r][c]);
        __syncthreads();
#pragma unroll
        for (int r = 0; r < 4; ++r) {
            float4 o; o.x = acc[r][0]; o.y = acc[r][1]; o.z = acc[r][2]; o.w = acc[r][3];
            *(float4*)&sH[(4 * tn + r) * HST + 4 * tj] = o;
        }
        __syncthreads();
    }

    // z[n] = h_n . v : partial over this thread's 4 cols, reduce across 16 tj lanes
    float vv[4];
#pragma unroll
    for (int c = 0; c < 4; ++c) vv[c] = sV[4 * tj + c];
#pragma unroll
    for (int r = 0; r < 4; ++r) {
        float p = 0.0f;
#pragma unroll
        for (int c = 0; c < 4; ++c)
            p = fmaf(sH[(4 * tn + r) * HST + 4 * tj + c], vv[c], p);
#pragma unroll
        for (int m = 1; m < 16; m <<= 1) p += __shfl_xor(p, m, 64);
        const int n = n0 + 4 * tn + r;
        if (tj == 0 && n < N) z[n] = p;
    }
}

// dinv = rsqrt(deg); u = dinv*z
__global__ void k_u(const float* __restrict__ deg, const float* __restrict__ z,
                    float* __restrict__ dinv, float* __restrict__ u, int N) {
    int n = blockIdx.x * blockDim.x + threadIdx.x;
    if (n >= N) return;
    float d = __frsqrt_rn(deg[n]);
    dinv[n] = d;
    u[n] = d * z[n];
}

// S[d] += u[s] over all edges (u is 400KB -> L2-resident)
__global__ void k_edge(const int* __restrict__ ei, const float* __restrict__ u,
                       float* __restrict__ S, int E) {
    int e = blockIdx.x * blockDim.x + threadIdx.x;
    if (e >= E) return;
    int s = ei[2 * e + 0];
    int d = ei[2 * e + 1];
    atomicAdd(&S[d], u[s]);
}

// out = dinv*S + dinv^2*z + c
__global__ void k_final(const float* __restrict__ dinv, const float* __restrict__ S,
                        const float* __restrict__ z, const float* __restrict__ c,
                        float* __restrict__ out, int N) {
    int n = blockIdx.x * blockDim.x + threadIdx.x;
    if (n >= N) return;
    float d = dinv[n];
    out[n] = fmaf(d, S[n] + d * z[n], *c);
}

extern "C" void kernel_launch(void* const* d_in, const int* in_sizes, int n_in,
                              void* d_out, int out_size, void* d_ws, size_t ws_size,
                              hipStream_t stream)
{
    const float* x     = (const float*)d_in[0];
    const int*   ei    = (const int*)d_in[1];
    const float* W_ih  = (const float*)d_in[2];
    const float* b_ih  = (const float*)d_in[3];
    const float* W_hh  = (const float*)d_in[4];
    const float* b_hh  = (const float*)d_in[5];
    const float* W_gcn = (const float*)d_in[6];
    const float* b_gcn = (const float*)d_in[7];
    const float* W_fc  = (const float*)d_in[8];
    const float* b_fc  = (const float*)d_in[9];
    float* out = (float*)d_out;

    const int N = in_sizes[0] / TT;
    const int E = in_sizes[1] / 2;

    char* ws = (char*)d_ws;
    size_t off = 0;
    auto alloc = [&](size_t bytes) { void* p = ws + off; off += (bytes + 255) & ~(size_t)255; return p; };
    float* deg  = (float*)alloc((size_t)N * 4);
    float* S    = (float*)alloc((size_t)N * 4);
    float* z    = (float*)alloc((size_t)N * 4);
    float* dinv = (float*)alloc((size_t)N * 4);
    float* u    = (float*)alloc((size_t)N * 4);
    float* v    = (float*)alloc(HH * 4);
    float* c    = (float*)alloc(4);

    k_dinit<<<(N + 255) / 256, 256, 0, stream>>>(deg, S, N);
    k_deg  <<<(E + 255) / 256, 256, 0, stream>>>(ei, deg, E);
    k_prep <<<1, 64, 0, stream>>>(W_gcn, b_gcn, W_fc, b_fc, v, c);
    k_rnn  <<<(N + NB - 1) / NB, 256, 0, stream>>>(x, W_ih, b_ih, W_hh, b_hh, v, z, N);
    k_u    <<<(N + 255) / 256, 256, 0, stream>>>(deg, z, dinv, u, N);
    k_edge <<<(E + 255) / 256, 256, 0, stream>>>(ei, u, S, E);
    k_final<<<(N + 255) / 256, 256, 0, stream>>>(dinv, S, z, c, out, N);
}